// Round 1
// 804.624 us; speedup vs baseline: 1.0051x; 1.0051x over previous
//
#include <hip/hip_runtime.h>

// Gray-Scott residual kernel, v2.
// Input tensor: (T=50, C=2, Y=100, X=100, Z=100) float32, strides:
//   t: 2,000,000  c: 1,000,000  y: 10,000  x: 100  z: 1
// Output: f_u (48,96,96,96) then f_v (48,96,96,96), concatenated flat.
//
// Changes vs v1 (374 us/dispatch, FETCH 814 MB vs ~392 MB ideal):
//  1. XCD-aware bijective block swizzle: blocks round-robin XCDs (b%8); a
//     (t,oy)-slab is NOT a multiple of 8 blocks, so y-neighbor slabs landed on
//     different XCD L2s and re-fetched shared y-planes from HBM (2.1x
//     over-fetch). Give each XCD a contiguous chunk of the work space so
//     y/t-neighbor tiles hit the same 4 MB L2.
//  2. 2 z-outputs per thread via float2 (all taps stay 8B-aligned since oz is
//     even): halves load/store instruction count, doubles per-thread MLP.
//  3. Nontemporal stores: the 340 MB output stream is never re-read; don't
//     let it evict input planes from L2.

#define N_OUT (48 * 96 * 96 * 96)   // 42,467,328 per channel
#define NPAIR (N_OUT / 2)           // 21,233,664 z-pairs
#define NBLK  (NPAIR / 256)         // 82,944 blocks (exact)
#define CHUNK (NBLK / 8)            // 10,368 blocks per XCD = 6 t-steps

typedef float f2 __attribute__((ext_vector_type(2)));

__global__ __launch_bounds__(256) void grayscott_kernel(
    const float* __restrict__ in, float* __restrict__ out) {
  // Bijective XCD swizzle (NBLK % 8 == 0): launched block b executes on XCD
  // b%8; work index wb walks (t, oy, ox, oz) contiguously within each XCD.
  const int b = blockIdx.x;
  const int wb = (b & 7) * CHUNK + (b >> 3);
  const int vid = wb * 256 + (int)threadIdx.x;

  // vid = ((t*96 + oy)*96 + ox)*48 + ozp   (oz = 2*ozp)
  const int ozp = vid % 48;
  int tmp = vid / 48;
  const int ox = tmp % 96;
  tmp /= 96;
  const int oy = tmp % 96;
  const int t = tmp / 96;

  const int iz = ozp * 2 + 2;  // even -> every tap offset is 8B-aligned
  const int ix = ox + 2;
  const int iy = oy + 2;

  // Max byte offset ~400MB < 2^31: 32-bit indexing is safe.
  const int base = t * 2000000 + iy * 10000 + ix * 100 + iz;
  const float* __restrict__ u = in + base;            // channel 0
  const float* __restrict__ v = in + base + 1000000;  // channel 1

#define LD2(p) (*(const f2*)(p))

  const f2 uzm  = LD2(u - 2);        // [iz-2, iz-1]
  const f2 ucc  = LD2(u);            // [iz,   iz+1]  (the two centers)
  const f2 uzp  = LD2(u + 2);        // [iz+2, iz+3]
  const f2 uxm1 = LD2(u - 100);
  const f2 uxp1 = LD2(u + 100);
  const f2 uxm2 = LD2(u - 200);
  const f2 uxp2 = LD2(u + 200);
  const f2 uym1 = LD2(u - 10000);
  const f2 uyp1 = LD2(u + 10000);
  const f2 uym2 = LD2(u - 20000);
  const f2 uyp2 = LD2(u + 20000);
  const f2 un   = LD2(u + 2000000);  // t+1, same spatial point

  const f2 vzm  = LD2(v - 2);
  const f2 vcc  = LD2(v);
  const f2 vzp  = LD2(v + 2);
  const f2 vxm1 = LD2(v - 100);
  const f2 vxp1 = LD2(v + 100);
  const f2 vxm2 = LD2(v - 200);
  const f2 vxp2 = LD2(v + 200);
  const f2 vym1 = LD2(v - 10000);
  const f2 vyp1 = LD2(v + 10000);
  const f2 vym2 = LD2(v - 20000);
  const f2 vyp2 = LD2(v + 20000);
  const f2 vn   = LD2(v + 2000000);

  const float c0 = -1.0f / 12.0f;  // taps at +/-2
  const float c1 = 4.0f / 3.0f;    // taps at +/-1
  const float cc = -7.5f;          // combined center (3 * -5/2)
  const float inv_dx2 = 0.2304f;   // 1/DX^2, DX = 100/48

  f2 fu, fv;

  // ---- element 0: z = iz ----
  {
    float lap_u = cc * ucc.x
        + c1 * (ucc.y + uzm.y + uxp1.x + uxm1.x + uyp1.x + uym1.x)
        + c0 * (uzp.x + uzm.x + uxp2.x + uxm2.x + uyp2.x + uym2.x);
    float lap_v = cc * vcc.x
        + c1 * (vcc.y + vzm.y + vxp1.x + vxm1.x + vyp1.x + vym1.x)
        + c0 * (vzp.x + vzm.x + vxp2.x + vxm2.x + vyp2.x + vym2.x);
    lap_u *= inv_dx2;
    lap_v *= inv_dx2;
    const float uv2 = ucc.x * vcc.x * vcc.x;
    fu.x = 0.2f * lap_u - uv2 + 0.025f * (1.0f - ucc.x) - (un.x - ucc.x) * 2.0f;
    fv.x = 0.1f * lap_v + uv2 - 0.08f * vcc.x - (vn.x - vcc.x) * 2.0f;
  }

  // ---- element 1: z = iz + 1 ----
  {
    float lap_u = cc * ucc.y
        + c1 * (uzp.x + ucc.x + uxp1.y + uxm1.y + uyp1.y + uym1.y)
        + c0 * (uzp.y + uzm.y + uxp2.y + uxm2.y + uyp2.y + uym2.y);
    float lap_v = cc * vcc.y
        + c1 * (vzp.x + vcc.x + vxp1.y + vxm1.y + vyp1.y + vym1.y)
        + c0 * (vzp.y + vzm.y + vxp2.y + vxm2.y + vyp2.y + vym2.y);
    lap_u *= inv_dx2;
    lap_v *= inv_dx2;
    const float uv2 = ucc.y * vcc.y * vcc.y;
    fu.y = 0.2f * lap_u - uv2 + 0.025f * (1.0f - ucc.y) - (un.y - ucc.y) * 2.0f;
    fv.y = 0.1f * lap_v + uv2 - 0.08f * vcc.y - (vn.y - vcc.y) * 2.0f;
  }

  // Output flat index for this pair = 2*vid (oz is the fastest dim).
  __builtin_nontemporal_store(fu, (f2*)(out + 2 * vid));
  __builtin_nontemporal_store(fv, (f2*)(out + 2 * vid + N_OUT));
}

extern "C" void kernel_launch(void* const* d_in, const int* in_sizes, int n_in,
                              void* d_out, int out_size, void* d_ws, size_t ws_size,
                              hipStream_t stream) {
  const float* in = (const float*)d_in[0];
  float* out = (float*)d_out;
  grayscott_kernel<<<dim3(NBLK), dim3(256), 0, stream>>>(in, out);
}

// Round 2
// 743.810 us; speedup vs baseline: 1.0873x; 1.0818x over previous
//
#include <hip/hip_runtime.h>

// Gray-Scott residual kernel, v3.
// Input tensor: (T=50, C=2, Y=100, X=100, Z=100) float32, strides:
//   t: 2,000,000  c: 1,000,000  y: 10,000  x: 100  z: 1
// Output: f_u (48,96,96,96) then f_v (48,96,96,96), concatenated flat.
//
// v2 result: FETCH 814->360 MB but dur unchanged (370us) => latency-bound,
// not BW-bound. VGPR=28 => compiler batches loads, ~8-10 in flight per wave.
// v3: register-blocked 4-z strip per thread. 8 output values per thread from
// 40 aligned loads (5 VMEM/output vs 13), all independent => ~40 loads in
// flight per wave. Occupancy drops (~VGPR 110) but per-SIMD outstanding
// loads ~2.2x. Keeps XCD swizzle (the FETCH win) + nontemporal stores.

#define N_OUT (48 * 96 * 96 * 96)   // 42,467,328 per channel
#define NTHRD (N_OUT / 4)           // 10,616,832 threads (4 z each)
#define NBLK  (NTHRD / 256)         // 41,472 blocks (exact)
#define CHUNK (NBLK / 8)            // 5,184 blocks per XCD

typedef float f2 __attribute__((ext_vector_type(2)));
typedef float f4 __attribute__((ext_vector_type(4)));

#define LD4(p) (*(const f4*)(p))
#define LD2(p) (*(const f2*)(p))

__global__ __launch_bounds__(256) void grayscott_kernel(
    const float* __restrict__ in, float* __restrict__ out) {
  // Bijective XCD swizzle (NBLK % 8 == 0): block b runs on XCD b%8; work
  // index wb walks (t, oy, ox, z-strip) contiguously within each XCD so
  // y/t-neighbor tiles share that XCD's L2.
  const int b = blockIdx.x;
  const int wb = (b & 7) * CHUNK + (b >> 3);
  const int vid = wb * 256 + (int)threadIdx.x;

  // vid = ((t*96 + oy)*96 + ox)*24 + zq   (thread covers oz = 4*zq .. 4*zq+3)
  const int zq = vid % 24;
  int tmp = vid / 24;
  const int ox = tmp % 96;
  tmp /= 96;
  const int oy = tmp % 96;
  const int t = tmp / 96;

  const int ix = ox + 2;
  const int iy = oy + 2;

  // Pointer at z = 4*zq (quad-aligned). Centers for j=0..3 sit at +2..+5;
  // z-taps span +0..+7 (two aligned float4). All float2 taps are 8B-aligned.
  const int base = t * 2000000 + iy * 10000 + ix * 100 + 4 * zq;
  const float* __restrict__ u = in + base;            // channel 0
  const float* __restrict__ v = in + base + 1000000;  // channel 1

  // ---- issue all 40 loads as one independent cluster ----
  const f4 uza = LD4(u);          const f4 vza = LD4(v);
  const f4 uzb = LD4(u + 4);      const f4 vzb = LD4(v + 4);

  const f2 uxm1a = LD2(u - 100 + 2),   uxm1b = LD2(u - 100 + 4);
  const f2 uxp1a = LD2(u + 100 + 2),   uxp1b = LD2(u + 100 + 4);
  const f2 uxm2a = LD2(u - 200 + 2),   uxm2b = LD2(u - 200 + 4);
  const f2 uxp2a = LD2(u + 200 + 2),   uxp2b = LD2(u + 200 + 4);
  const f2 uym1a = LD2(u - 10000 + 2), uym1b = LD2(u - 10000 + 4);
  const f2 uyp1a = LD2(u + 10000 + 2), uyp1b = LD2(u + 10000 + 4);
  const f2 uym2a = LD2(u - 20000 + 2), uym2b = LD2(u - 20000 + 4);
  const f2 uyp2a = LD2(u + 20000 + 2), uyp2b = LD2(u + 20000 + 4);
  const f2 utna  = LD2(u + 2000000 + 2), utnb = LD2(u + 2000000 + 4);

  const f2 vxm1a = LD2(v - 100 + 2),   vxm1b = LD2(v - 100 + 4);
  const f2 vxp1a = LD2(v + 100 + 2),   vxp1b = LD2(v + 100 + 4);
  const f2 vxm2a = LD2(v - 200 + 2),   vxm2b = LD2(v - 200 + 4);
  const f2 vxp2a = LD2(v + 200 + 2),   vxp2b = LD2(v + 200 + 4);
  const f2 vym1a = LD2(v - 10000 + 2), vym1b = LD2(v - 10000 + 4);
  const f2 vyp1a = LD2(v + 10000 + 2), vyp1b = LD2(v + 10000 + 4);
  const f2 vym2a = LD2(v - 20000 + 2), vym2b = LD2(v - 20000 + 4);
  const f2 vyp2a = LD2(v + 20000 + 2), vyp2b = LD2(v + 20000 + 4);
  const f2 vtna  = LD2(v + 2000000 + 2), vtnb = LD2(v + 2000000 + 4);

  // ---- unpack to compile-time-indexed arrays (fully unrolled below) ----
  const float uzv[8] = {uza.x, uza.y, uza.z, uza.w, uzb.x, uzb.y, uzb.z, uzb.w};
  const float vzv[8] = {vza.x, vza.y, vza.z, vza.w, vzb.x, vzb.y, vzb.z, vzb.w};

  const float uxm1[4] = {uxm1a.x, uxm1a.y, uxm1b.x, uxm1b.y};
  const float uxp1[4] = {uxp1a.x, uxp1a.y, uxp1b.x, uxp1b.y};
  const float uxm2[4] = {uxm2a.x, uxm2a.y, uxm2b.x, uxm2b.y};
  const float uxp2[4] = {uxp2a.x, uxp2a.y, uxp2b.x, uxp2b.y};
  const float uym1[4] = {uym1a.x, uym1a.y, uym1b.x, uym1b.y};
  const float uyp1[4] = {uyp1a.x, uyp1a.y, uyp1b.x, uyp1b.y};
  const float uym2[4] = {uym2a.x, uym2a.y, uym2b.x, uym2b.y};
  const float uyp2[4] = {uyp2a.x, uyp2a.y, uyp2b.x, uyp2b.y};
  const float utn[4]  = {utna.x,  utna.y,  utnb.x,  utnb.y};

  const float vxm1[4] = {vxm1a.x, vxm1a.y, vxm1b.x, vxm1b.y};
  const float vxp1[4] = {vxp1a.x, vxp1a.y, vxp1b.x, vxp1b.y};
  const float vxm2[4] = {vxm2a.x, vxm2a.y, vxm2b.x, vxm2b.y};
  const float vxp2[4] = {vxp2a.x, vxp2a.y, vxp2b.x, vxp2b.y};
  const float vym1[4] = {vym1a.x, vym1a.y, vym1b.x, vym1b.y};
  const float vyp1[4] = {vyp1a.x, vyp1a.y, vyp1b.x, vyp1b.y};
  const float vym2[4] = {vym2a.x, vym2a.y, vym2b.x, vym2b.y};
  const float vyp2[4] = {vyp2a.x, vyp2a.y, vyp2b.x, vyp2b.y};
  const float vtn[4]  = {vtna.x,  vtna.y,  vtnb.x,  vtnb.y};

  const float c0 = -1.0f / 12.0f;  // taps at +/-2
  const float c1 = 4.0f / 3.0f;    // taps at +/-1
  const float cc = -7.5f;          // combined center (3 * -5/2)
  const float inv_dx2 = 0.2304f;   // 1/DX^2, DX = 100/48

  f4 fu, fv;
#pragma unroll
  for (int j = 0; j < 4; ++j) {
    const float uc = uzv[j + 2];
    const float vc = vzv[j + 2];
    float lap_u = cc * uc
        + c1 * (uzv[j + 1] + uzv[j + 3] + uxp1[j] + uxm1[j] + uyp1[j] + uym1[j])
        + c0 * (uzv[j] + uzv[j + 4] + uxp2[j] + uxm2[j] + uyp2[j] + uym2[j]);
    float lap_v = cc * vc
        + c1 * (vzv[j + 1] + vzv[j + 3] + vxp1[j] + vxm1[j] + vyp1[j] + vym1[j])
        + c0 * (vzv[j] + vzv[j + 4] + vxp2[j] + vxm2[j] + vyp2[j] + vym2[j]);
    lap_u *= inv_dx2;
    lap_v *= inv_dx2;
    const float uv2 = uc * vc * vc;
    fu[j] = 0.2f * lap_u - uv2 + 0.025f * (1.0f - uc) - (utn[j] - uc) * 2.0f;
    fv[j] = 0.1f * lap_v + uv2 - 0.08f * vc - (vtn[j] - vc) * 2.0f;
  }

  // Output flat index = 4*vid (oz fastest); 16B-aligned.
  __builtin_nontemporal_store(fu, (f4*)(out + 4 * vid));
  __builtin_nontemporal_store(fv, (f4*)(out + 4 * vid + N_OUT));
}

extern "C" void kernel_launch(void* const* d_in, const int* in_sizes, int n_in,
                              void* d_out, int out_size, void* d_ws, size_t ws_size,
                              hipStream_t stream) {
  const float* in = (const float*)d_in[0];
  float* out = (float*)d_out;
  grayscott_kernel<<<dim3(NBLK), dim3(256), 0, stream>>>(in, out);
}